// Round 6
// baseline (2120.175 us; speedup 1.0000x reference)
//
#include <hip/hip_runtime.h>
#include <math.h>

#define CDIM 256
#define SDIM 4096
#define NBATCH 4

typedef _Float16 f16;
typedef _Float16 f16x4 __attribute__((ext_vector_type(4)));
typedef _Float16 f16x8 __attribute__((ext_vector_type(8)));
typedef float    f32x16 __attribute__((ext_vector_type(16)));

union PK2 { f16 h[2]; unsigned u; };
union CV8 { f16x8 v; uint2 q[2]; };

// async 16B global->LDS DMA; LDS dest wave-uniform base, HW scatters lane*16.
__device__ __forceinline__ void gload_lds16(const f16* gp, void* lp) {
    __builtin_amdgcn_global_load_lds(
        (const __attribute__((address_space(1))) void*)gp,
        (__attribute__((address_space(3))) void*)lp, 16, 0, 0);
}

// MFMA frag model (validated rounds 2-5, mfma_f32_32x32x16_f16):
//   A[m][k]: m=lane&31, frag j covers k=16j+8*(lane>>5)+(0..7)
//   B[k][n]: n=lane&31, same k pattern
//   C/D:     col=lane&31, row=(r&3)+8*(r>>2)+4*(lane>>5)

// ---------------------------------------------------------------------------
// Kernel 1: MFMA 1x1-conv projections. One proj per blockIdx.z (n*3+p).
// Tile 128 c_out x 128 s, K=256 in 4 chunks of 64, dbuf LDS, W frags resident.
//   theta_t/phi_t: (s,c) f16 via LDS transpose; g: (c,s) f16 direct.
// ---------------------------------------------------------------------------
__global__ __launch_bounds__(256, 2)
void proj_kernel(const float* __restrict__ x,
                 const float* __restrict__ Wt, const float* __restrict__ bt,
                 const float* __restrict__ Wp, const float* __restrict__ bp,
                 const float* __restrict__ Wg, const float* __restrict__ bg,
                 f16* __restrict__ theta_t, f16* __restrict__ phi_t,
                 f16* __restrict__ g_out)
{
    const int p = blockIdx.z % 3;
    const int n = blockIdx.z / 3;
    const float* W    = (p == 0) ? Wt : (p == 1) ? Wp : Wg;
    const float* bias = (p == 0) ? bt : (p == 1) ? bp : bg;
    const float* xb = x + (size_t)n * CDIM * SDIM;
    const int s0 = blockIdx.x * 128;
    const int m0 = blockIdx.y * 128;

    __shared__ __align__(16) char smraw[34816];
    unsigned (*xs)[128][34] = reinterpret_cast<unsigned (*)[128][34]>(smraw);
    f16 (*tr)[136]          = reinterpret_cast<f16 (*)[136]>(smraw);

    const int t = threadIdx.x, w = t >> 6, l = t & 63, ln = l & 31, hi = l >> 5;
    const int wm = w & 1, wn = w >> 1;

    f16x8 aW[2][16];
    #pragma unroll
    for (int mt = 0; mt < 2; ++mt) {
        const float* wr = W + (size_t)(m0 + 64 * wm + 32 * mt + ln) * CDIM + 8 * hi;
        #pragma unroll
        for (int j = 0; j < 16; ++j) {
            float4 u0 = *(const float4*)(wr + 16 * j);
            float4 u1 = *(const float4*)(wr + 16 * j + 4);
            f16x8 v;
            v[0] = (f16)u0.x; v[1] = (f16)u0.y; v[2] = (f16)u0.z; v[3] = (f16)u0.w;
            v[4] = (f16)u1.x; v[5] = (f16)u1.y; v[6] = (f16)u1.z; v[7] = (f16)u1.w;
            aW[mt][j] = v;
        }
    }

    f32x16 acc[2][2];
    #pragma unroll
    for (int a = 0; a < 2; ++a)
        #pragma unroll
        for (int b = 0; b < 2; ++b)
            #pragma unroll
            for (int r = 0; r < 16; ++r) acc[a][b][r] = 0.0f;

    const int sL = t & 127;
    const int kB = (t >> 7) * 32;

    float xv[32];
#define PLOAD(k0)                                                             \
    { _Pragma("unroll")                                                       \
      for (int i = 0; i < 32; ++i)                                            \
          xv[i] = xb[(size_t)((k0) + kB + i) * SDIM + s0 + sL]; }
#define PWRITE(b)                                                             \
    { _Pragma("unroll")                                                       \
      for (int m = 0; m < 16; ++m) {                                          \
          PK2 pk; pk.h[0] = (f16)xv[2 * m]; pk.h[1] = (f16)xv[2 * m + 1];     \
          xs[b][sL][(kB >> 1) + m] = pk.u; } }

    PLOAD(0);
    for (int ci = 0; ci < 4; ++ci) {
        const int b = ci & 1;
        PWRITE(b);
        __syncthreads();
        if (ci < 3) PLOAD((ci + 1) * 64);
        #pragma unroll
        for (int j = 0; j < 4; ++j) {
            f16x8 bx[2];
            #pragma unroll
            for (int nt = 0; nt < 2; ++nt) {
                const unsigned* pr = &xs[b][64 * wn + 32 * nt + ln][8 * j + 4 * hi];
                f16x4 lo = *(const f16x4*)pr;
                f16x4 h4 = *(const f16x4*)(pr + 2);
                f16x8 bb;
                bb[0]=lo[0]; bb[1]=lo[1]; bb[2]=lo[2]; bb[3]=lo[3];
                bb[4]=h4[0]; bb[5]=h4[1]; bb[6]=h4[2]; bb[7]=h4[3];
                bx[nt] = bb;
            }
            #pragma unroll
            for (int mt = 0; mt < 2; ++mt)
                #pragma unroll
                for (int nt = 0; nt < 2; ++nt)
                    acc[mt][nt] = __builtin_amdgcn_mfma_f32_32x32x16_f16(
                        aW[mt][ci * 4 + j], bx[nt], acc[mt][nt], 0, 0, 0);
        }
    }
#undef PLOAD
#undef PWRITE

    float bv[2][16];
    #pragma unroll
    for (int mt = 0; mt < 2; ++mt)
        #pragma unroll
        for (int r = 0; r < 16; ++r)
            bv[mt][r] = bias[m0 + 64 * wm + 32 * mt + (r & 3) + 8 * (r >> 2) + 4 * hi];

    __syncthreads();
    if (p < 2) {
        #pragma unroll
        for (int mt = 0; mt < 2; ++mt)
            #pragma unroll
            for (int nt = 0; nt < 2; ++nt)
                #pragma unroll
                for (int r = 0; r < 16; ++r)
                    tr[64 * wn + 32 * nt + ln]
                      [64 * wm + 32 * mt + (r & 3) + 8 * (r >> 2) + 4 * hi] =
                        (f16)(acc[mt][nt][r] + bv[mt][r]);
        __syncthreads();
        f16* out = ((p == 0) ? theta_t : phi_t) + (size_t)n * SDIM * CDIM;
        const int row = t >> 1, ch = (t & 1) * 64;
        #pragma unroll
        for (int i = 0; i < 8; ++i)
            *(f16x8*)&out[(size_t)(s0 + row) * CDIM + m0 + ch + 8 * i] =
                *(const f16x8*)&tr[row][ch + 8 * i];
    } else {
        f16* out = g_out + (size_t)n * CDIM * SDIM;
        #pragma unroll
        for (int mt = 0; mt < 2; ++mt)
            #pragma unroll
            for (int nt = 0; nt < 2; ++nt)
                #pragma unroll
                for (int r = 0; r < 16; ++r)
                    out[(size_t)(m0 + 64 * wm + 32 * mt + (r & 3) + 8 * (r >> 2) + 4 * hi)
                        * SDIM + s0 + 64 * wn + 32 * nt + ln] =
                        (f16)(acc[mt][nt][r] + bv[mt][r]);
    }
}

// ---------------------------------------------------------------------------
// Kernel 2: MFMA flash attention; 4-way key split (2 blocks/CU); S^T
// orientation; in-register softmax; phi via DMA, G via VGPR-prefetch +
// ds_write (fixes the 64-line DMA scatter of round 5). 1 barrier/chunk.
// ---------------------------------------------------------------------------
__global__ __launch_bounds__(256, 2)
void attn_kernel(const f16* __restrict__ theta,
                 const f16* __restrict__ phi,
                 const f16* __restrict__ g,
                 f16* __restrict__ Op,       // [4][n][s][c] unnormalized f16
                 float* __restrict__ pm,     // [4][n][s]
                 float* __restrict__ pl)     // [4][n][s]
{
    const int bx    = blockIdx.x;
    const int n     = bx >> 5;
    const int q0    = (bx & 31) * 128;
    const int split = blockIdx.y;
    const int koff  = split * (SDIM / 4);
    const int NCH   = (SDIM / 4) / 32;      // 32 chunks of 32 keys

    __shared__ f16x8 bufP[2][1024];         // 32 KB phi  [key][grp^key]
    __shared__ f16x8 bufG[2][1024];         // 32 KB G    [kg*256 + chan^(kg<<2)]

    const int t  = threadIdx.x;
    const int w  = t >> 6;
    const int l  = t & 63;
    const int ln = l & 31;
    const int hi = l >> 5;

    const f16* thb = theta + (size_t)n * SDIM * CDIM;
    const f16* phb = phi   + (size_t)n * SDIM * CDIM;
    const f16* gb  = g     + (size_t)n * CDIM * SDIM;

    const int myq = q0 + 32 * w + ln;

    // G staging lane mapping: wave w covers chans [64w,64w+64); per it:
    // chan = 64w + 16it + (l>>2), kg = l&3 -> 64B-contiguous per chan row.
    const int gchanb = 64 * w + (l >> 2);
    const int gkg    = l & 3;

    f16x8 bT[16];
    {
        const f16* ap = thb + (size_t)myq * CDIM + hi * 8;
        #pragma unroll
        for (int j = 0; j < 16; ++j)
            bT[j] = *(const f16x8*)(ap + 16 * j);
    }

    f32x16 O[8];
    #pragma unroll
    for (int ct = 0; ct < 8; ++ct)
        #pragma unroll
        for (int r = 0; r < 16; ++r) O[ct][r] = 0.0f;

    float m_run = -INFINITY, l_run = 0.0f;

#define ISSUE_PHI(k0, b)                                                      \
    {                                                                         \
        _Pragma("unroll")                                                     \
        for (int it = 0; it < 4; ++it) {                                      \
            const int slot = w * 256 + it * 64 + l;                           \
            const int key  = slot >> 5;                                       \
            const int grp  = (slot & 31) ^ key;                               \
            gload_lds16(phb + (size_t)((k0) + key) * CDIM + grp * 8,          \
                        &bufP[b][w * 256 + it * 64]);                         \
        }                                                                     \
    }
#define GLOAD(k0, pb)                                                         \
    { _Pragma("unroll")                                                       \
      for (int it = 0; it < 4; ++it)                                          \
          gP[pb][it] = *(const f16x8*)(gb + (size_t)(gchanb + 16 * it) * SDIM \
                                       + (k0) + gkg * 8); }
#define GWRITE(pb, b)                                                         \
    { _Pragma("unroll")                                                       \
      for (int it = 0; it < 4; ++it) {                                        \
          const int chan = gchanb + 16 * it;                                  \
          bufG[b][gkg * 256 + (chan ^ (gkg << 2))] = gP[pb][it]; } }

    f16x8 gP[2][4];
    // prologue: phi-DMA(0); G(0)->regs->bufG[0]; G(1)->regs
    ISSUE_PHI(koff, 0);
    GLOAD(koff, 0);
    GWRITE(0, 0);
    if (NCH > 1) GLOAD(koff + 32, 1);

    for (int ci = 0; ci < NCH; ++ci) {
        const int b = ci & 1;
        __syncthreads();   // drains phi-DMA(ci); bufG[b] writes visible
        if (ci + 1 < NCH) {
            ISSUE_PHI(koff + (ci + 1) * 32, b ^ 1);
            GWRITE((ci + 1) & 1, b ^ 1);
        }
        if (ci + 2 < NCH) GLOAD(koff + (ci + 2) * 32, b);

        // ---- S^T = phi x theta^T ----
        f32x16 sC;
        #pragma unroll
        for (int r = 0; r < 16; ++r) sC[r] = 0.0f;
        #pragma unroll
        for (int j = 0; j < 16; ++j) {
            const int grp = 2 * j + hi;
            f16x8 a = bufP[b][ln * 32 + (grp ^ ln)];
            sC = __builtin_amdgcn_mfma_f32_32x32x16_f16(a, bT[j], sC, 0, 0, 0);
        }

        // ---- in-register online softmax (lane pair holds all 32 keys) ----
        float mx = sC[0];
        #pragma unroll
        for (int r = 1; r < 16; ++r) mx = fmaxf(mx, sC[r]);
        mx = fmaxf(mx, __shfl_xor(mx, 32));
        const float mn = fmaxf(m_run, mx);
        const float al = __expf(m_run - mn);
        m_run = mn;
        float sum = 0.0f;
        #pragma unroll
        for (int r = 0; r < 16; ++r) {
            sC[r] = __expf(sC[r] - mn);
            sum += sC[r];
        }
        sum += __shfl_xor(sum, 32);
        l_run = l_run * al + sum;

        if (__any(al != 1.0f)) {
            #pragma unroll
            for (int ct = 0; ct < 8; ++ct)
                #pragma unroll
                for (int r = 0; r < 16; ++r) O[ct][r] *= al;
        }

        // ---- repack P to PV B-frags ----
        f16x8 pf[2];
        #pragma unroll
        for (int ks = 0; ks < 2; ++ks) {
            #pragma unroll
            for (int j = 0; j < 4; ++j) {
                const float own = hi ? sC[8 * ks + 4 + j] : sC[8 * ks + j];
                const float oth = hi ? sC[8 * ks + j]     : sC[8 * ks + 4 + j];
                const float par = __shfl_xor(oth, 32);
                pf[ks][j]     = (f16)(hi ? par : own);
                pf[ks][4 + j] = (f16)(hi ? own : par);
            }
        }

        // ---- PV: O^T += G x P^T ----
        #pragma unroll
        for (int ks = 0; ks < 2; ++ks) {
            const int kg = 2 * ks + hi;
            #pragma unroll
            for (int ct = 0; ct < 8; ++ct) {
                f16x8 ga = bufG[b][kg * 256 + ((32 * ct + ln) ^ (kg << 2))];
                O[ct] = __builtin_amdgcn_mfma_f32_32x32x16_f16(ga, pf[ks], O[ct], 0, 0, 0);
            }
        }
    }
#undef ISSUE_PHI
#undef GLOAD
#undef GWRITE

    // ---- epilogue: per-wave LDS transpose -> Op (s,c) f16, + (m,l) ----
    __syncthreads();
    {
        f16* tw = (f16*)bufP + (size_t)w * 1152;   // per-wave [32 q][36 c]
        f16* Opb = Op + ((size_t)(split * NBATCH + n)) * SDIM * CDIM;
        const int q  = l >> 1;
        const int ch = (l & 1) * 16;
        #pragma unroll
        for (int ct = 0; ct < 8; ++ct) {
            #pragma unroll
            for (int q4 = 0; q4 < 4; ++q4) {
                f16x4 v;
                v[0] = (f16)O[ct][4 * q4 + 0];
                v[1] = (f16)O[ct][4 * q4 + 1];
                v[2] = (f16)O[ct][4 * q4 + 2];
                v[3] = (f16)O[ct][4 * q4 + 3];
                *(f16x4*)&tw[ln * 36 + 8 * q4 + 4 * hi] = v;
            }
            f16x4 r0 = *(const f16x4*)&tw[q * 36 + ch + 0];
            f16x4 r1 = *(const f16x4*)&tw[q * 36 + ch + 4];
            f16x4 r2 = *(const f16x4*)&tw[q * 36 + ch + 8];
            f16x4 r3 = *(const f16x4*)&tw[q * 36 + ch + 12];
            f16x8 o0, o1;
            o0[0]=r0[0]; o0[1]=r0[1]; o0[2]=r0[2]; o0[3]=r0[3];
            o0[4]=r1[0]; o0[5]=r1[1]; o0[6]=r1[2]; o0[7]=r1[3];
            o1[0]=r2[0]; o1[1]=r2[1]; o1[2]=r2[2]; o1[3]=r2[3];
            o1[4]=r3[0]; o1[5]=r3[1]; o1[6]=r3[2]; o1[7]=r3[3];
            f16* dst = Opb + (size_t)(q0 + 32 * w + q) * CDIM + 32 * ct + ch;
            *(f16x8*)(dst)     = o0;
            *(f16x8*)(dst + 8) = o1;
        }
        if (hi == 0) {
            pm[(size_t)(split * NBATCH + n) * SDIM + myq] = m_run;
            pl[(size_t)(split * NBATCH + n) * SDIM + myq] = l_run;
        }
    }
}

// ---------------------------------------------------------------------------
// Kernel 3: MFMA output projection + residual; 4-way split combine fused
// into staging via precomputed per-s scales.
// ---------------------------------------------------------------------------
__global__ __launch_bounds__(256, 2)
void outproj_kernel(const f16* __restrict__ Op,
                    const float* __restrict__ pm,
                    const float* __restrict__ pl,
                    const float* __restrict__ Wo,
                    const float* __restrict__ bo,
                    const float* __restrict__ x,
                    float* __restrict__ out)
{
    const int n  = blockIdx.z;
    const int s0 = blockIdx.x * 128;
    const int m0 = blockIdx.y * 128;

    __shared__ __align__(16) unsigned ys[2][128][34];
    __shared__ float scs[4][128];

    const int t = threadIdx.x, w = t >> 6, l = t & 63, ln = l & 31, hi = l >> 5;
    const int wm = w & 1, wn = w >> 1;

    if (t < 128) {
        const int s = s0 + t;
        float mv[4], lv[4];
        float M = -INFINITY;
        #pragma unroll
        for (int i = 0; i < 4; ++i) {
            mv[i] = pm[((size_t)i * NBATCH + n) * SDIM + s];
            lv[i] = pl[((size_t)i * NBATCH + n) * SDIM + s];
            M = fmaxf(M, mv[i]);
        }
        float d = 0.0f, e[4];
        #pragma unroll
        for (int i = 0; i < 4; ++i) { e[i] = __expf(mv[i] - M); d += e[i] * lv[i]; }
        const float rd = 1.0f / d;
        #pragma unroll
        for (int i = 0; i < 4; ++i) scs[i][t] = e[i] * rd;
    }

    f16x8 aW[2][16];
    #pragma unroll
    for (int mt = 0; mt < 2; ++mt) {
        const float* wr = Wo + (size_t)(m0 + 64 * wm + 32 * mt + ln) * CDIM + 8 * hi;
        #pragma unroll
        for (int j = 0; j < 16; ++j) {
            float4 u0 = *(const float4*)(wr + 16 * j);
            float4 u1 = *(const float4*)(wr + 16 * j + 4);
            f16x8 v;
            v[0] = (f16)u0.x; v[1] = (f16)u0.y; v[2] = (f16)u0.z; v[3] = (f16)u0.w;
            v[4] = (f16)u1.x; v[5] = (f16)u1.y; v[6] = (f16)u1.z; v[7] = (f16)u1.w;
            aW[mt][j] = v;
        }
    }

    f32x16 acc[2][2];
    #pragma unroll
    for (int a = 0; a < 2; ++a)
        #pragma unroll
        for (int b = 0; b < 2; ++b)
            #pragma unroll
            for (int r = 0; r < 16; ++r) acc[a][b][r] = 0.0f;

    const f16* Opb[4];
    #pragma unroll
    for (int i = 0; i < 4; ++i)
        Opb[i] = Op + ((size_t)i * NBATCH + n) * SDIM * CDIM;

    __syncthreads();

    f16x8 yv[4];
#define OLOAD(k0)                                                             \
    { _Pragma("unroll")                                                       \
      for (int u4 = 0; u4 < 4; ++u4) {                                        \
          const int u = u4 * 256 + t;                                         \
          const int kg = u & 7, sl = u >> 3;                                  \
          const size_t off = (size_t)(s0 + sl) * CDIM + (k0) + 8 * kg;        \
          f16x8 a0 = *(const f16x8*)(Opb[0] + off);                           \
          f16x8 a1 = *(const f16x8*)(Opb[1] + off);                           \
          f16x8 a2 = *(const f16x8*)(Opb[2] + off);                           \
          f16x8 a3 = *(const f16x8*)(Opb[3] + off);                           \
          const float c0 = scs[0][sl], c1 = scs[1][sl];                       \
          const float c2 = scs[2][sl], c3 = scs[3][sl];                       \
          f16x8 r;                                                            \
          _Pragma("unroll")                                                   \
          for (int e = 0; e < 8; ++e)                                         \
              r[e] = (f16)(c0 * (float)a0[e] + c1 * (float)a1[e] +            \
                           c2 * (float)a2[e] + c3 * (float)a3[e]);            \
          yv[u4] = r; } }
#define OWRITE(b)                                                             \
    { _Pragma("unroll")                                                       \
      for (int u4 = 0; u4 < 4; ++u4) {                                        \
          const int u = u4 * 256 + t;                                         \
          const int kg = u & 7, sl = u >> 3;                                  \
          CV8 cv; cv.v = yv[u4];                                              \
          *(uint2*)&ys[b][sl][4 * kg]     = cv.q[0];                          \
          *(uint2*)&ys[b][sl][4 * kg + 2] = cv.q[1]; } }

    OLOAD(0);
    for (int ci = 0; ci < 4; ++ci) {
        const int b = ci & 1;
        OWRITE(b);
        __syncthreads();
        if (ci < 3) OLOAD((ci + 1) * 64);
        #pragma unroll
        for (int j = 0; j < 4; ++j) {
            f16x8 bx[2];
            #pragma unroll
            for (int nt = 0; nt < 2; ++nt) {
                const unsigned* pr = &ys[b][64 * wn + 32 * nt + ln][8 * j + 4 * hi];
                f16x4 lo = *(const f16x4*)pr;
                f16x4 h4 = *(const f16x4*)(pr + 2);
                f16x8 bb;
                bb[0]=lo[0]; bb[1]=lo[1]; bb[2]=lo[2]; bb[3]=lo[3];
                bb[4]=h4[0]; bb[5]=h4[1]; bb[6]=h4[2]; bb[7]=h4[3];
                bx[nt] = bb;
            }
            #pragma unroll
            for (int mt = 0; mt < 2; ++mt)
                #pragma unroll
                for (int nt = 0; nt < 2; ++nt)
                    acc[mt][nt] = __builtin_amdgcn_mfma_f32_32x32x16_f16(
                        aW[mt][ci * 4 + j], bx[nt], acc[mt][nt], 0, 0, 0);
        }
    }
#undef OLOAD
#undef OWRITE

    const float* xb = x + (size_t)n * CDIM * SDIM;
    float* ob = out + (size_t)n * CDIM * SDIM;
    #pragma unroll
    for (int mt = 0; mt < 2; ++mt)
        #pragma unroll
        for (int r = 0; r < 16; ++r) {
            const int c = m0 + 64 * wm + 32 * mt + (r & 3) + 8 * (r >> 2) + 4 * hi;
            const float bv = bo[c];
            #pragma unroll
            for (int nt = 0; nt < 2; ++nt) {
                const size_t idx = (size_t)c * SDIM + s0 + 64 * wn + 32 * nt + ln;
                ob[idx] = acc[mt][nt][r] + bv + xb[idx];
            }
        }
}

// ---------------------------------------------------------------------------
extern "C" void kernel_launch(void* const* d_in, const int* in_sizes, int n_in,
                              void* d_out, int out_size, void* d_ws, size_t ws_size,
                              hipStream_t stream)
{
    const float* x  = (const float*)d_in[0];
    const float* Wg = (const float*)d_in[1];
    const float* bg = (const float*)d_in[2];
    const float* Wt = (const float*)d_in[3];
    const float* bt = (const float*)d_in[4];
    const float* Wp = (const float*)d_in[5];
    const float* bp = (const float*)d_in[6];
    const float* Wo = (const float*)d_in[7];
    const float* bo = (const float*)d_in[8];

    const size_t half_buf = (size_t)NBATCH * CDIM * SDIM * sizeof(f16);   // 8 MB
    const size_t mlbuf    = (size_t)4 * NBATCH * SDIM * sizeof(float);    // 256 KB
    char* wsb = (char*)d_ws;
    f16*   theta = (f16*)(wsb);
    f16*   phi   = (f16*)(wsb + half_buf);
    f16*   g     = (f16*)(wsb + 2 * half_buf);
    f16*   Op    = (f16*)(wsb + 3 * half_buf);               // 4 splits, 33.6 MB
    float* pm    = (float*)(wsb + 7 * half_buf);
    float* pl    = (float*)(wsb + 7 * half_buf + mlbuf);
    float* out   = (float*)d_out;

    proj_kernel<<<dim3(SDIM / 128, CDIM / 128, NBATCH * 3), 256, 0, stream>>>(
        x, Wt, bt, Wp, bp, Wg, bg, theta, phi, g);
    attn_kernel<<<dim3(NBATCH * (SDIM / 128), 4), 256, 0, stream>>>(
        theta, phi, g, Op, pm, pl);
    outproj_kernel<<<dim3(SDIM / 128, CDIM / 128, NBATCH), 256, 0, stream>>>(
        Op, pm, pl, Wo, bo, x, out);
}

// Round 7
// 272.801 us; speedup vs baseline: 7.7719x; 7.7719x over previous
//
#include <hip/hip_runtime.h>
#include <math.h>

#define CDIM 256
#define SDIM 4096
#define NBATCH 4

typedef _Float16 f16;
typedef _Float16 f16x4 __attribute__((ext_vector_type(4)));
typedef _Float16 f16x8 __attribute__((ext_vector_type(8)));
typedef float    f32x16 __attribute__((ext_vector_type(16)));

union PK2 { f16 h[2]; unsigned u; };
union CV8 { f16x8 v; uint2 q[2]; };

// async 16B global->LDS DMA; LDS dest wave-uniform base, HW scatters lane*16.
__device__ __forceinline__ void gload_lds16(const f16* gp, void* lp) {
    __builtin_amdgcn_global_load_lds(
        (const __attribute__((address_space(1))) void*)gp,
        (__attribute__((address_space(3))) void*)lp, 16, 0, 0);
}

// MFMA frag model (validated rounds 2-6, mfma_f32_32x32x16_f16):
//   A[m][k]: m=lane&31, frag covers k=16*step+8*(lane>>5)+(0..7)
//   B[k][n]: n=lane&31, same k pattern
//   C/D:     col=lane&31, row=(r&3)+8*(r>>2)+4*(lane>>5)

// ---------------------------------------------------------------------------
// Kernel 1: MFMA 1x1-conv projections (unchanged from round 5 — measured ok).
// ---------------------------------------------------------------------------
__global__ __launch_bounds__(256, 2)
void proj_kernel(const float* __restrict__ x,
                 const float* __restrict__ Wt, const float* __restrict__ bt,
                 const float* __restrict__ Wp, const float* __restrict__ bp,
                 const float* __restrict__ Wg, const float* __restrict__ bg,
                 f16* __restrict__ theta_t, f16* __restrict__ phi_t,
                 f16* __restrict__ g_out)
{
    const int p = blockIdx.z % 3;
    const int n = blockIdx.z / 3;
    const float* W    = (p == 0) ? Wt : (p == 1) ? Wp : Wg;
    const float* bias = (p == 0) ? bt : (p == 1) ? bp : bg;
    const float* xb = x + (size_t)n * CDIM * SDIM;
    const int s0 = blockIdx.x * 128;
    const int m0 = blockIdx.y * 128;

    __shared__ __align__(16) char smraw[34816];
    unsigned (*xs)[128][34] = reinterpret_cast<unsigned (*)[128][34]>(smraw);
    f16 (*tr)[136]          = reinterpret_cast<f16 (*)[136]>(smraw);

    const int t = threadIdx.x, w = t >> 6, l = t & 63, ln = l & 31, hi = l >> 5;
    const int wm = w & 1, wn = w >> 1;

    f16x8 aW[2][16];
    #pragma unroll
    for (int mt = 0; mt < 2; ++mt) {
        const float* wr = W + (size_t)(m0 + 64 * wm + 32 * mt + ln) * CDIM + 8 * hi;
        #pragma unroll
        for (int j = 0; j < 16; ++j) {
            float4 u0 = *(const float4*)(wr + 16 * j);
            float4 u1 = *(const float4*)(wr + 16 * j + 4);
            f16x8 v;
            v[0] = (f16)u0.x; v[1] = (f16)u0.y; v[2] = (f16)u0.z; v[3] = (f16)u0.w;
            v[4] = (f16)u1.x; v[5] = (f16)u1.y; v[6] = (f16)u1.z; v[7] = (f16)u1.w;
            aW[mt][j] = v;
        }
    }

    f32x16 acc[2][2];
    #pragma unroll
    for (int a = 0; a < 2; ++a)
        #pragma unroll
        for (int b = 0; b < 2; ++b)
            #pragma unroll
            for (int r = 0; r < 16; ++r) acc[a][b][r] = 0.0f;

    const int sL = t & 127;
    const int kB = (t >> 7) * 32;

    float xv[32];
#define PLOAD(k0)                                                             \
    { _Pragma("unroll")                                                       \
      for (int i = 0; i < 32; ++i)                                            \
          xv[i] = xb[(size_t)((k0) + kB + i) * SDIM + s0 + sL]; }
#define PWRITE(b)                                                             \
    { _Pragma("unroll")                                                       \
      for (int m = 0; m < 16; ++m) {                                          \
          PK2 pk; pk.h[0] = (f16)xv[2 * m]; pk.h[1] = (f16)xv[2 * m + 1];     \
          xs[b][sL][(kB >> 1) + m] = pk.u; } }

    PLOAD(0);
    for (int ci = 0; ci < 4; ++ci) {
        const int b = ci & 1;
        PWRITE(b);
        __syncthreads();
        if (ci < 3) PLOAD((ci + 1) * 64);
        #pragma unroll
        for (int j = 0; j < 4; ++j) {
            f16x8 bx[2];
            #pragma unroll
            for (int nt = 0; nt < 2; ++nt) {
                const unsigned* pr = &xs[b][64 * wn + 32 * nt + ln][8 * j + 4 * hi];
                f16x4 lo = *(const f16x4*)pr;
                f16x4 h4 = *(const f16x4*)(pr + 2);
                f16x8 bb;
                bb[0]=lo[0]; bb[1]=lo[1]; bb[2]=lo[2]; bb[3]=lo[3];
                bb[4]=h4[0]; bb[5]=h4[1]; bb[6]=h4[2]; bb[7]=h4[3];
                bx[nt] = bb;
            }
            #pragma unroll
            for (int mt = 0; mt < 2; ++mt)
                #pragma unroll
                for (int nt = 0; nt < 2; ++nt)
                    acc[mt][nt] = __builtin_amdgcn_mfma_f32_32x32x16_f16(
                        aW[mt][ci * 4 + j], bx[nt], acc[mt][nt], 0, 0, 0);
        }
    }
#undef PLOAD
#undef PWRITE

    float bv[2][16];
    #pragma unroll
    for (int mt = 0; mt < 2; ++mt)
        #pragma unroll
        for (int r = 0; r < 16; ++r)
            bv[mt][r] = bias[m0 + 64 * wm + 32 * mt + (r & 3) + 8 * (r >> 2) + 4 * hi];

    __syncthreads();
    if (p < 2) {
        #pragma unroll
        for (int mt = 0; mt < 2; ++mt)
            #pragma unroll
            for (int nt = 0; nt < 2; ++nt)
                #pragma unroll
                for (int r = 0; r < 16; ++r)
                    tr[64 * wn + 32 * nt + ln]
                      [64 * wm + 32 * mt + (r & 3) + 8 * (r >> 2) + 4 * hi] =
                        (f16)(acc[mt][nt][r] + bv[mt][r]);
        __syncthreads();
        f16* out = ((p == 0) ? theta_t : phi_t) + (size_t)n * SDIM * CDIM;
        const int row = t >> 1, ch = (t & 1) * 64;
        #pragma unroll
        for (int i = 0; i < 8; ++i)
            *(f16x8*)&out[(size_t)(s0 + row) * CDIM + m0 + ch + 8 * i] =
                *(const f16x8*)&tr[row][ch + 8 * i];
    } else {
        f16* out = g_out + (size_t)n * CDIM * SDIM;
        #pragma unroll
        for (int mt = 0; mt < 2; ++mt)
            #pragma unroll
            for (int nt = 0; nt < 2; ++nt)
                #pragma unroll
                for (int r = 0; r < 16; ++r)
                    out[(size_t)(m0 + 64 * wm + 32 * mt + (r & 3) + 8 * (r >> 2) + 4 * hi)
                        * SDIM + s0 + 64 * wn + 32 * nt + ln] =
                        (f16)(acc[mt][nt][r] + bv[mt][r]);
    }
}

// ---------------------------------------------------------------------------
// Kernel 2: MFMA flash attention. 64-key chunks (full-cache-line G DMA),
// all staging via global_load_lds, double-buffered 128 KB LDS, 1 block/CU,
// 2-way key split. In-register softmax over 2 S-tiles. No reg prefetch
// (round 6 lesson: 128-AGPR accumulator + extra regs at (256,2) spills).
//
// bufP granule slot = key*32 + (grp ^ (key&31))        [32 KB / chunk]
// bufG granule slot = chan*8 + (kg ^ (chan&7))         [32 KB / chunk]
// Both slot orders are lane-consecutive for the DMA writer.
// ---------------------------------------------------------------------------
__global__ __launch_bounds__(256, 1)
void attn_kernel(const f16* __restrict__ theta,
                 const f16* __restrict__ phi,
                 const f16* __restrict__ g,
                 f16* __restrict__ Op,       // [2][n][s][c] unnormalized f16
                 float* __restrict__ pm,     // [2][n][s]
                 float* __restrict__ pl)     // [2][n][s]
{
    const int bx    = blockIdx.x;
    const int n     = bx >> 5;
    const int q0    = (bx & 31) * 128;
    const int split = blockIdx.y;
    const int koff  = split * (SDIM / 2);
    const int NCH   = (SDIM / 2) / 64;      // 32 chunks of 64 keys

    __shared__ f16x8 bufP[2][2048];         // 64 KB phi [key 0..63][grp^key]
    __shared__ f16x8 bufG[2][2048];         // 64 KB G   [chan][kg^chan]

    const int t  = threadIdx.x;
    const int w  = t >> 6;
    const int l  = t & 63;
    const int ln = l & 31;
    const int hi = l >> 5;

    const f16* thb = theta + (size_t)n * SDIM * CDIM;
    const f16* phb = phi   + (size_t)n * SDIM * CDIM;
    const f16* gb  = g     + (size_t)n * CDIM * SDIM;

    const int myq = q0 + 32 * w + ln;

    // theta B-fragments (resident, 64 VGPRs)
    f16x8 bT[16];
    {
        const f16* ap = thb + (size_t)myq * CDIM + hi * 8;
        #pragma unroll
        for (int j = 0; j < 16; ++j)
            bT[j] = *(const f16x8*)(ap + 16 * j);
    }

    f32x16 O[8];
    #pragma unroll
    for (int ct = 0; ct < 8; ++ct)
        #pragma unroll
        for (int r = 0; r < 16; ++r) O[ct][r] = 0.0f;

    float m_run = -INFINITY, l_run = 0.0f;

    // wave w owns granule slots [w*512, w*512+512) of each buffer: 8 DMA
    // instructions of 64 lanes each.
#define ISSUE_CHUNK(k0, b)                                                    \
    {                                                                         \
        _Pragma("unroll")                                                     \
        for (int it = 0; it < 8; ++it) {                                      \
            const int slot = w * 512 + it * 64 + l;                           \
            const int key  = slot >> 5;                                       \
            const int grp  = (slot & 31) ^ (key & 31);                        \
            gload_lds16(phb + (size_t)((k0) + key) * CDIM + grp * 8,          \
                        &bufP[b][w * 512 + it * 64]);                         \
        }                                                                     \
        _Pragma("unroll")                                                     \
        for (int it = 0; it < 8; ++it) {                                      \
            const int slot = w * 512 + it * 64 + l;                           \
            const int chan = slot >> 3;                                       \
            const int kg   = (slot & 7) ^ (chan & 7);                         \
            gload_lds16(gb + (size_t)chan * SDIM + (k0) + kg * 8,             \
                        &bufG[b][w * 512 + it * 64]);                         \
        }                                                                     \
    }

    ISSUE_CHUNK(koff, 0);

    for (int ci = 0; ci < NCH; ++ci) {
        const int b = ci & 1;
        __syncthreads();   // drains DMA for chunk ci; frees buffer b^1
        if (ci + 1 < NCH) ISSUE_CHUNK(koff + (ci + 1) * 64, b ^ 1);

        // ---- S^T = phi x theta^T : 64 keys (2 M-tiles) x 32 q, K=256 ----
        f32x16 sC[2];
        #pragma unroll
        for (int mt = 0; mt < 2; ++mt)
            #pragma unroll
            for (int r = 0; r < 16; ++r) sC[mt][r] = 0.0f;
        #pragma unroll
        for (int j = 0; j < 16; ++j) {
            const int grp = 2 * j + hi;
            f16x8 a0 = bufP[b][(ln)      * 32 + (grp ^ ln)];
            f16x8 a1 = bufP[b][(32 + ln) * 32 + (grp ^ ln)];
            sC[0] = __builtin_amdgcn_mfma_f32_32x32x16_f16(a0, bT[j], sC[0], 0, 0, 0);
            sC[1] = __builtin_amdgcn_mfma_f32_32x32x16_f16(a1, bT[j], sC[1], 0, 0, 0);
        }
        // lane (ln,hi) tile mt reg r: key = 32mt + (r&3)+8(r>>2)+4hi, q = myq

        // ---- in-register online softmax over 64 keys ----
        float mx = sC[0][0];
        #pragma unroll
        for (int r = 1; r < 16; ++r) mx = fmaxf(mx, sC[0][r]);
        #pragma unroll
        for (int r = 0; r < 16; ++r) mx = fmaxf(mx, sC[1][r]);
        mx = fmaxf(mx, __shfl_xor(mx, 32));
        const float mn = fmaxf(m_run, mx);
        const float al = __expf(m_run - mn);
        m_run = mn;
        float sum = 0.0f;
        #pragma unroll
        for (int mt = 0; mt < 2; ++mt)
            #pragma unroll
            for (int r = 0; r < 16; ++r) {
                sC[mt][r] = __expf(sC[mt][r] - mn);
                sum += sC[mt][r];
            }
        sum += __shfl_xor(sum, 32);
        l_run = l_run * al + sum;

        if (__any(al != 1.0f)) {
            #pragma unroll
            for (int ct = 0; ct < 8; ++ct)
                #pragma unroll
                for (int r = 0; r < 16; ++r) O[ct][r] *= al;
        }

        // ---- repack P to PV B-frags: pf[ks][i] = P[key=16ks+8hi+i][myq] ----
        f16x8 pf[4];
        #pragma unroll
        for (int ks = 0; ks < 4; ++ks) {
            const int mt = ks >> 1;
            const int bq = 8 * (ks & 1);
            #pragma unroll
            for (int j = 0; j < 4; ++j) {
                const float own = hi ? sC[mt][bq + 4 + j] : sC[mt][bq + j];
                const float oth = hi ? sC[mt][bq + j]     : sC[mt][bq + 4 + j];
                const float par = __shfl_xor(oth, 32);
                pf[ks][j]     = (f16)(hi ? par : own);
                pf[ks][4 + j] = (f16)(hi ? own : par);
            }
        }

        // ---- PV: O^T += G x P^T (256 chan x 32 q, K=64 keys) ----
        #pragma unroll
        for (int ks = 0; ks < 4; ++ks) {
            const int kg = 2 * ks + hi;
            #pragma unroll
            for (int ct = 0; ct < 8; ++ct) {
                f16x8 ga = bufG[b][(32 * ct + ln) * 8 + (kg ^ (ln & 7))];
                O[ct] = __builtin_amdgcn_mfma_f32_32x32x16_f16(ga, pf[ks], O[ct], 0, 0, 0);
            }
        }
    }
#undef ISSUE_CHUNK

    // ---- epilogue: per-wave LDS transpose -> Op (s,c) f16, + (m,l) ----
    __syncthreads();
    {
        f16* tw = (f16*)bufP + (size_t)w * 1152;   // per-wave [32 q][36 c]
        f16* Opb = Op + ((size_t)(split * NBATCH + n)) * SDIM * CDIM;
        const int q  = l >> 1;
        const int ch = (l & 1) * 16;
        #pragma unroll
        for (int ct = 0; ct < 8; ++ct) {
            #pragma unroll
            for (int q4 = 0; q4 < 4; ++q4) {
                f16x4 v;
                v[0] = (f16)O[ct][4 * q4 + 0];
                v[1] = (f16)O[ct][4 * q4 + 1];
                v[2] = (f16)O[ct][4 * q4 + 2];
                v[3] = (f16)O[ct][4 * q4 + 3];
                *(f16x4*)&tw[ln * 36 + 8 * q4 + 4 * hi] = v;
            }
            f16x4 r0 = *(const f16x4*)&tw[q * 36 + ch + 0];
            f16x4 r1 = *(const f16x4*)&tw[q * 36 + ch + 4];
            f16x4 r2 = *(const f16x4*)&tw[q * 36 + ch + 8];
            f16x4 r3 = *(const f16x4*)&tw[q * 36 + ch + 12];
            f16x8 o0, o1;
            o0[0]=r0[0]; o0[1]=r0[1]; o0[2]=r0[2]; o0[3]=r0[3];
            o0[4]=r1[0]; o0[5]=r1[1]; o0[6]=r1[2]; o0[7]=r1[3];
            o1[0]=r2[0]; o1[1]=r2[1]; o1[2]=r2[2]; o1[3]=r2[3];
            o1[4]=r3[0]; o1[5]=r3[1]; o1[6]=r3[2]; o1[7]=r3[3];
            f16* dst = Opb + (size_t)(q0 + 32 * w + q) * CDIM + 32 * ct + ch;
            *(f16x8*)(dst)     = o0;
            *(f16x8*)(dst + 8) = o1;
        }
        if (hi == 0) {
            pm[(size_t)(split * NBATCH + n) * SDIM + myq] = m_run;
            pl[(size_t)(split * NBATCH + n) * SDIM + myq] = l_run;
        }
    }
}

// ---------------------------------------------------------------------------
// Kernel 3: MFMA output projection + residual; 2-way split combine fused
// into staging via precomputed per-s scales.
// ---------------------------------------------------------------------------
__global__ __launch_bounds__(256, 2)
void outproj_kernel(const f16* __restrict__ Op,
                    const float* __restrict__ pm,
                    const float* __restrict__ pl,
                    const float* __restrict__ Wo,
                    const float* __restrict__ bo,
                    const float* __restrict__ x,
                    float* __restrict__ out)
{
    const int n  = blockIdx.z;
    const int s0 = blockIdx.x * 128;
    const int m0 = blockIdx.y * 128;

    __shared__ __align__(16) unsigned ys[2][128][34];
    __shared__ float scs[2][128];

    const int t = threadIdx.x, w = t >> 6, l = t & 63, ln = l & 31, hi = l >> 5;
    const int wm = w & 1, wn = w >> 1;

    if (t < 128) {
        const int s = s0 + t;
        float mv[2], lv[2];
        #pragma unroll
        for (int i = 0; i < 2; ++i) {
            mv[i] = pm[((size_t)i * NBATCH + n) * SDIM + s];
            lv[i] = pl[((size_t)i * NBATCH + n) * SDIM + s];
        }
        const float M  = fmaxf(mv[0], mv[1]);
        const float e0 = __expf(mv[0] - M);
        const float e1 = __expf(mv[1] - M);
        const float rd = 1.0f / (e0 * lv[0] + e1 * lv[1]);
        scs[0][t] = e0 * rd;
        scs[1][t] = e1 * rd;
    }

    f16x8 aW[2][16];
    #pragma unroll
    for (int mt = 0; mt < 2; ++mt) {
        const float* wr = Wo + (size_t)(m0 + 64 * wm + 32 * mt + ln) * CDIM + 8 * hi;
        #pragma unroll
        for (int j = 0; j < 16; ++j) {
            float4 u0 = *(const float4*)(wr + 16 * j);
            float4 u1 = *(const float4*)(wr + 16 * j + 4);
            f16x8 v;
            v[0] = (f16)u0.x; v[1] = (f16)u0.y; v[2] = (f16)u0.z; v[3] = (f16)u0.w;
            v[4] = (f16)u1.x; v[5] = (f16)u1.y; v[6] = (f16)u1.z; v[7] = (f16)u1.w;
            aW[mt][j] = v;
        }
    }

    f32x16 acc[2][2];
    #pragma unroll
    for (int a = 0; a < 2; ++a)
        #pragma unroll
        for (int b = 0; b < 2; ++b)
            #pragma unroll
            for (int r = 0; r < 16; ++r) acc[a][b][r] = 0.0f;

    const f16* Opb[2];
    #pragma unroll
    for (int i = 0; i < 2; ++i)
        Opb[i] = Op + ((size_t)i * NBATCH + n) * SDIM * CDIM;

    __syncthreads();

    f16x8 yv[4];
#define OLOAD(k0)                                                             \
    { _Pragma("unroll")                                                       \
      for (int u4 = 0; u4 < 4; ++u4) {                                        \
          const int u = u4 * 256 + t;                                         \
          const int kg = u & 7, sl = u >> 3;                                  \
          const size_t off = (size_t)(s0 + sl) * CDIM + (k0) + 8 * kg;        \
          f16x8 a0 = *(const f16x8*)(Opb[0] + off);                           \
          f16x8 a1 = *(const f16x8*)(Opb[1] + off);                           \
          const float c0 = scs[0][sl], c1 = scs[1][sl];                       \
          f16x8 r;                                                            \
          _Pragma("unroll")                                                   \
          for (int e = 0; e < 8; ++e)                                         \
              r[e] = (f16)(c0 * (float)a0[e] + c1 * (float)a1[e]);            \
          yv[u4] = r; } }
#define OWRITE(b)                                                             \
    { _Pragma("unroll")                                                       \
      for (int u4 = 0; u4 < 4; ++u4) {                                        \
          const int u = u4 * 256 + t;                                         \
          const int kg = u & 7, sl = u >> 3;                                  \
          CV8 cv; cv.v = yv[u4];                                              \
          *(uint2*)&ys[b][sl][4 * kg]     = cv.q[0];                          \
          *(uint2*)&ys[b][sl][4 * kg + 2] = cv.q[1]; } }

    OLOAD(0);
    for (int ci = 0; ci < 4; ++ci) {
        const int b = ci & 1;
        OWRITE(b);
        __syncthreads();
        if (ci < 3) OLOAD((ci + 1) * 64);
        #pragma unroll
        for (int j = 0; j < 4; ++j) {
            f16x8 bx[2];
            #pragma unroll
            for (int nt = 0; nt < 2; ++nt) {
                const unsigned* pr = &ys[b][64 * wn + 32 * nt + ln][8 * j + 4 * hi];
                f16x4 lo = *(const f16x4*)pr;
                f16x4 h4 = *(const f16x4*)(pr + 2);
                f16x8 bb;
                bb[0]=lo[0]; bb[1]=lo[1]; bb[2]=lo[2]; bb[3]=lo[3];
                bb[4]=h4[0]; bb[5]=h4[1]; bb[6]=h4[2]; bb[7]=h4[3];
                bx[nt] = bb;
            }
            #pragma unroll
            for (int mt = 0; mt < 2; ++mt)
                #pragma unroll
                for (int nt = 0; nt < 2; ++nt)
                    acc[mt][nt] = __builtin_amdgcn_mfma_f32_32x32x16_f16(
                        aW[mt][ci * 4 + j], bx[nt], acc[mt][nt], 0, 0, 0);
        }
    }
#undef OLOAD
#undef OWRITE

    const float* xb = x + (size_t)n * CDIM * SDIM;
    float* ob = out + (size_t)n * CDIM * SDIM;
    #pragma unroll
    for (int mt = 0; mt < 2; ++mt)
        #pragma unroll
        for (int r = 0; r < 16; ++r) {
            const int c = m0 + 64 * wm + 32 * mt + (r & 3) + 8 * (r >> 2) + 4 * hi;
            const float bv = bo[c];
            #pragma unroll
            for (int nt = 0; nt < 2; ++nt) {
                const size_t idx = (size_t)c * SDIM + s0 + 64 * wn + 32 * nt + ln;
                ob[idx] = acc[mt][nt][r] + bv + xb[idx];
            }
        }
}

// ---------------------------------------------------------------------------
extern "C" void kernel_launch(void* const* d_in, const int* in_sizes, int n_in,
                              void* d_out, int out_size, void* d_ws, size_t ws_size,
                              hipStream_t stream)
{
    const float* x  = (const float*)d_in[0];
    const float* Wg = (const float*)d_in[1];
    const float* bg = (const float*)d_in[2];
    const float* Wt = (const float*)d_in[3];
    const float* bt = (const float*)d_in[4];
    const float* Wp = (const float*)d_in[5];
    const float* bp = (const float*)d_in[6];
    const float* Wo = (const float*)d_in[7];
    const float* bo = (const float*)d_in[8];

    const size_t half_buf = (size_t)NBATCH * CDIM * SDIM * sizeof(f16);   // 8 MB
    const size_t mlbuf    = (size_t)2 * NBATCH * SDIM * sizeof(float);    // 128 KB
    char* wsb = (char*)d_ws;
    f16*   theta = (f16*)(wsb);
    f16*   phi   = (f16*)(wsb + half_buf);
    f16*   g     = (f16*)(wsb + 2 * half_buf);
    f16*   Op    = (f16*)(wsb + 3 * half_buf);               // 2 splits, 16 MB
    float* pm    = (float*)(wsb + 5 * half_buf);
    float* pl    = (float*)(wsb + 5 * half_buf + mlbuf);
    float* out   = (float*)d_out;

    proj_kernel<<<dim3(SDIM / 128, CDIM / 128, NBATCH * 3), 256, 0, stream>>>(
        x, Wt, bt, Wp, bp, Wg, bg, theta, phi, g);
    attn_kernel<<<dim3(NBATCH * (SDIM / 128), 2), 256, 0, stream>>>(
        theta, phi, g, Op, pm, pl);
    outproj_kernel<<<dim3(SDIM / 128, CDIM / 128, NBATCH), 256, 0, stream>>>(
        Op, pm, pl, Wo, bo, x, out);
}

// Round 8
// 254.023 us; speedup vs baseline: 8.3464x; 1.0739x over previous
//
#include <hip/hip_runtime.h>
#include <math.h>

#define CDIM 256
#define SDIM 4096
#define NBATCH 4

typedef _Float16 f16;
typedef _Float16 f16x4 __attribute__((ext_vector_type(4)));
typedef _Float16 f16x8 __attribute__((ext_vector_type(8)));
typedef float    f32x16 __attribute__((ext_vector_type(16)));

union PK2 { f16 h[2]; unsigned u; };
union CV8 { f16x8 v; uint2 q[2]; };

// async 16B global->LDS DMA; LDS dest wave-uniform base, HW scatters lane*16.
__device__ __forceinline__ void gload_lds16(const f16* gp, void* lp) {
    __builtin_amdgcn_global_load_lds(
        (const __attribute__((address_space(1))) void*)gp,
        (__attribute__((address_space(3))) void*)lp, 16, 0, 0);
}

// MFMA frag model (validated rounds 2-7, mfma_f32_32x32x16_f16):
//   A[m][k]: m=lane&31, frag covers k=16*step+8*(lane>>5)+(0..7)
//   B[k][n]: n=lane&31, same k pattern
//   C/D:     col=lane&31, row=(r&3)+8*(r>>2)+4*(lane>>5)

// ---------------------------------------------------------------------------
// Kernel 1: MFMA 1x1-conv projections (unchanged — measured ok).
// ---------------------------------------------------------------------------
__global__ __launch_bounds__(256, 2)
void proj_kernel(const float* __restrict__ x,
                 const float* __restrict__ Wt, const float* __restrict__ bt,
                 const float* __restrict__ Wp, const float* __restrict__ bp,
                 const float* __restrict__ Wg, const float* __restrict__ bg,
                 f16* __restrict__ theta_t, f16* __restrict__ phi_t,
                 f16* __restrict__ g_out)
{
    const int p = blockIdx.z % 3;
    const int n = blockIdx.z / 3;
    const float* W    = (p == 0) ? Wt : (p == 1) ? Wp : Wg;
    const float* bias = (p == 0) ? bt : (p == 1) ? bp : bg;
    const float* xb = x + (size_t)n * CDIM * SDIM;
    const int s0 = blockIdx.x * 128;
    const int m0 = blockIdx.y * 128;

    __shared__ __align__(16) char smraw[34816];
    unsigned (*xs)[128][34] = reinterpret_cast<unsigned (*)[128][34]>(smraw);
    f16 (*tr)[136]          = reinterpret_cast<f16 (*)[136]>(smraw);

    const int t = threadIdx.x, w = t >> 6, l = t & 63, ln = l & 31, hi = l >> 5;
    const int wm = w & 1, wn = w >> 1;

    f16x8 aW[2][16];
    #pragma unroll
    for (int mt = 0; mt < 2; ++mt) {
        const float* wr = W + (size_t)(m0 + 64 * wm + 32 * mt + ln) * CDIM + 8 * hi;
        #pragma unroll
        for (int j = 0; j < 16; ++j) {
            float4 u0 = *(const float4*)(wr + 16 * j);
            float4 u1 = *(const float4*)(wr + 16 * j + 4);
            f16x8 v;
            v[0] = (f16)u0.x; v[1] = (f16)u0.y; v[2] = (f16)u0.z; v[3] = (f16)u0.w;
            v[4] = (f16)u1.x; v[5] = (f16)u1.y; v[6] = (f16)u1.z; v[7] = (f16)u1.w;
            aW[mt][j] = v;
        }
    }

    f32x16 acc[2][2];
    #pragma unroll
    for (int a = 0; a < 2; ++a)
        #pragma unroll
        for (int b = 0; b < 2; ++b)
            #pragma unroll
            for (int r = 0; r < 16; ++r) acc[a][b][r] = 0.0f;

    const int sL = t & 127;
    const int kB = (t >> 7) * 32;

    float xv[32];
#define PLOAD(k0)                                                             \
    { _Pragma("unroll")                                                       \
      for (int i = 0; i < 32; ++i)                                            \
          xv[i] = xb[(size_t)((k0) + kB + i) * SDIM + s0 + sL]; }
#define PWRITE(b)                                                             \
    { _Pragma("unroll")                                                       \
      for (int m = 0; m < 16; ++m) {                                          \
          PK2 pk; pk.h[0] = (f16)xv[2 * m]; pk.h[1] = (f16)xv[2 * m + 1];     \
          xs[b][sL][(kB >> 1) + m] = pk.u; } }

    PLOAD(0);
    for (int ci = 0; ci < 4; ++ci) {
        const int b = ci & 1;
        PWRITE(b);
        __syncthreads();
        if (ci < 3) PLOAD((ci + 1) * 64);
        #pragma unroll
        for (int j = 0; j < 4; ++j) {
            f16x8 bx[2];
            #pragma unroll
            for (int nt = 0; nt < 2; ++nt) {
                const unsigned* pr = &xs[b][64 * wn + 32 * nt + ln][8 * j + 4 * hi];
                f16x4 lo = *(const f16x4*)pr;
                f16x4 h4 = *(const f16x4*)(pr + 2);
                f16x8 bb;
                bb[0]=lo[0]; bb[1]=lo[1]; bb[2]=lo[2]; bb[3]=lo[3];
                bb[4]=h4[0]; bb[5]=h4[1]; bb[6]=h4[2]; bb[7]=h4[3];
                bx[nt] = bb;
            }
            #pragma unroll
            for (int mt = 0; mt < 2; ++mt)
                #pragma unroll
                for (int nt = 0; nt < 2; ++nt)
                    acc[mt][nt] = __builtin_amdgcn_mfma_f32_32x32x16_f16(
                        aW[mt][ci * 4 + j], bx[nt], acc[mt][nt], 0, 0, 0);
        }
    }
#undef PLOAD
#undef PWRITE

    float bv[2][16];
    #pragma unroll
    for (int mt = 0; mt < 2; ++mt)
        #pragma unroll
        for (int r = 0; r < 16; ++r)
            bv[mt][r] = bias[m0 + 64 * wm + 32 * mt + (r & 3) + 8 * (r >> 2) + 4 * hi];

    __syncthreads();
    if (p < 2) {
        #pragma unroll
        for (int mt = 0; mt < 2; ++mt)
            #pragma unroll
            for (int nt = 0; nt < 2; ++nt)
                #pragma unroll
                for (int r = 0; r < 16; ++r)
                    tr[64 * wn + 32 * nt + ln]
                      [64 * wm + 32 * mt + (r & 3) + 8 * (r >> 2) + 4 * hi] =
                        (f16)(acc[mt][nt][r] + bv[mt][r]);
        __syncthreads();
        f16* out = ((p == 0) ? theta_t : phi_t) + (size_t)n * SDIM * CDIM;
        const int row = t >> 1, ch = (t & 1) * 64;
        #pragma unroll
        for (int i = 0; i < 8; ++i)
            *(f16x8*)&out[(size_t)(s0 + row) * CDIM + m0 + ch + 8 * i] =
                *(const f16x8*)&tr[row][ch + 8 * i];
    } else {
        f16* out = g_out + (size_t)n * CDIM * SDIM;
        #pragma unroll
        for (int mt = 0; mt < 2; ++mt)
            #pragma unroll
            for (int nt = 0; nt < 2; ++nt)
                #pragma unroll
                for (int r = 0; r < 16; ++r)
                    out[(size_t)(m0 + 64 * wm + 32 * mt + (r & 3) + 8 * (r >> 2) + 4 * hi)
                        * SDIM + s0 + 64 * wn + 32 * nt + ln] =
                        (f16)(acc[mt][nt][r] + bv[mt][r]);
    }
}

// ---------------------------------------------------------------------------
// Kernel 2: MFMA flash attention. 32-key chunks, double-buffered 64 KB LDS
// -> 2 blocks/CU (round 5 occupancy) + line-friendly chan-major G DMA
// (round 7 fix). 4-way key split, 1 barrier/chunk. Register shape kept at
// exactly 256 unified regs (bT 64 + O 128 + sC/pf) — round 6 proved +32 spills.
//
// bufP slot = key*32 + (grp ^ key)                      [16 KB / chunk]
// bufG slot = chan*4 + (kg ^ (chan&3) ^ ((chan>>2)&3))  [16 KB / chunk]
//   G DMA instr: 16 chans x 64 B contiguous; PV read: 8 consecutive lanes
//   cover all 8 bank-groups (conflict-free).
// ---------------------------------------------------------------------------
__global__ __launch_bounds__(256, 2)
void attn_kernel(const f16* __restrict__ theta,
                 const f16* __restrict__ phi,
                 const f16* __restrict__ g,
                 f16* __restrict__ Op,       // [4][n][s][c] unnormalized f16
                 float* __restrict__ pm,     // [4][n][s]
                 float* __restrict__ pl)     // [4][n][s]
{
    const int bx    = blockIdx.x;
    const int n     = bx >> 5;
    const int q0    = (bx & 31) * 128;
    const int split = blockIdx.y;
    const int koff  = split * (SDIM / 4);
    const int NCH   = (SDIM / 4) / 32;      // 32 chunks of 32 keys

    __shared__ f16x8 bufP[2][1024];         // 32 KB phi [key][grp^key]
    __shared__ f16x8 bufG[2][1024];         // 32 KB G   [chan][kg swizzled]

    const int t  = threadIdx.x;
    const int w  = t >> 6;
    const int l  = t & 63;
    const int ln = l & 31;
    const int hi = l >> 5;

    const f16* thb = theta + (size_t)n * SDIM * CDIM;
    const f16* phb = phi   + (size_t)n * SDIM * CDIM;
    const f16* gb  = g     + (size_t)n * CDIM * SDIM;

    const int myq = q0 + 32 * w + ln;

    // theta B-fragments (resident, 64 VGPRs)
    f16x8 bT[16];
    {
        const f16* ap = thb + (size_t)myq * CDIM + hi * 8;
        #pragma unroll
        for (int j = 0; j < 16; ++j)
            bT[j] = *(const f16x8*)(ap + 16 * j);
    }

    f32x16 O[8];
    #pragma unroll
    for (int ct = 0; ct < 8; ++ct)
        #pragma unroll
        for (int r = 0; r < 16; ++r) O[ct][r] = 0.0f;

    float m_run = -INFINITY, l_run = 0.0f;

#define ISSUE_CHUNK(k0, b)                                                    \
    {                                                                         \
        _Pragma("unroll")                                                     \
        for (int it = 0; it < 4; ++it) {                                      \
            const int slot = w * 256 + it * 64 + l;                           \
            const int key  = slot >> 5;                                       \
            const int grp  = (slot & 31) ^ key;                               \
            gload_lds16(phb + (size_t)((k0) + key) * CDIM + grp * 8,          \
                        &bufP[b][w * 256 + it * 64]);                         \
        }                                                                     \
        _Pragma("unroll")                                                     \
        for (int it = 0; it < 4; ++it) {                                      \
            const int slot = w * 256 + it * 64 + l;                           \
            const int chan = slot >> 2;                                       \
            const int kg   = (slot & 3) ^ (chan & 3) ^ ((chan >> 2) & 3);     \
            gload_lds16(gb + (size_t)chan * SDIM + (k0) + kg * 8,             \
                        &bufG[b][w * 256 + it * 64]);                         \
        }                                                                     \
    }

    ISSUE_CHUNK(koff, 0);

    for (int ci = 0; ci < NCH; ++ci) {
        const int b = ci & 1;
        __syncthreads();   // drains DMA for chunk ci; frees buffer b^1
        if (ci + 1 < NCH) ISSUE_CHUNK(koff + (ci + 1) * 32, b ^ 1);

        // ---- S^T = phi x theta^T : 32 keys x 32 q, K=256 ----
        f32x16 sC;
        #pragma unroll
        for (int r = 0; r < 16; ++r) sC[r] = 0.0f;
        #pragma unroll
        for (int j = 0; j < 16; ++j) {
            const int grp = 2 * j + hi;
            f16x8 a = bufP[b][ln * 32 + (grp ^ ln)];
            sC = __builtin_amdgcn_mfma_f32_32x32x16_f16(a, bT[j], sC, 0, 0, 0);
        }
        // lane (ln,hi) reg r: key=(r&3)+8*(r>>2)+4hi, q=myq

        // ---- in-register online softmax ----
        float mx = sC[0];
        #pragma unroll
        for (int r = 1; r < 16; ++r) mx = fmaxf(mx, sC[r]);
        mx = fmaxf(mx, __shfl_xor(mx, 32));
        const float mn = fmaxf(m_run, mx);
        const float al = __expf(m_run - mn);
        m_run = mn;
        float sum = 0.0f;
        #pragma unroll
        for (int r = 0; r < 16; ++r) {
            sC[r] = __expf(sC[r] - mn);
            sum += sC[r];
        }
        sum += __shfl_xor(sum, 32);
        l_run = l_run * al + sum;

        if (__any(al != 1.0f)) {
            #pragma unroll
            for (int ct = 0; ct < 8; ++ct)
                #pragma unroll
                for (int r = 0; r < 16; ++r) O[ct][r] *= al;
        }

        // ---- repack P to PV B-frags: pf[ks][i] = P[key=16ks+8hi+i][myq] ----
        f16x8 pf[2];
        #pragma unroll
        for (int ks = 0; ks < 2; ++ks) {
            #pragma unroll
            for (int j = 0; j < 4; ++j) {
                const float own = hi ? sC[8 * ks + 4 + j] : sC[8 * ks + j];
                const float oth = hi ? sC[8 * ks + j]     : sC[8 * ks + 4 + j];
                const float par = __shfl_xor(oth, 32);
                pf[ks][j]     = (f16)(hi ? par : own);
                pf[ks][4 + j] = (f16)(hi ? own : par);
            }
        }

        // ---- PV: O^T += G x P^T (256 chan x 32 q, K=32 keys) ----
        #pragma unroll
        for (int ks = 0; ks < 2; ++ks) {
            const int kg = 2 * ks + hi;
            #pragma unroll
            for (int ct = 0; ct < 8; ++ct) {
                const int chan = 32 * ct + ln;
                f16x8 ga = bufG[b][chan * 4 + (kg ^ (ln & 3) ^ ((ln >> 2) & 3))];
                O[ct] = __builtin_amdgcn_mfma_f32_32x32x16_f16(ga, pf[ks], O[ct], 0, 0, 0);
            }
        }
    }
#undef ISSUE_CHUNK

    // ---- epilogue: per-wave LDS transpose -> Op (s,c) f16, + (m,l) ----
    __syncthreads();
    {
        f16* tw = (f16*)bufP + (size_t)w * 1152;   // per-wave [32 q][36 c]
        f16* Opb = Op + ((size_t)(split * NBATCH + n)) * SDIM * CDIM;
        const int q  = l >> 1;
        const int ch = (l & 1) * 16;
        #pragma unroll
        for (int ct = 0; ct < 8; ++ct) {
            #pragma unroll
            for (int q4 = 0; q4 < 4; ++q4) {
                f16x4 v;
                v[0] = (f16)O[ct][4 * q4 + 0];
                v[1] = (f16)O[ct][4 * q4 + 1];
                v[2] = (f16)O[ct][4 * q4 + 2];
                v[3] = (f16)O[ct][4 * q4 + 3];
                *(f16x4*)&tw[ln * 36 + 8 * q4 + 4 * hi] = v;
            }
            f16x4 r0 = *(const f16x4*)&tw[q * 36 + ch + 0];
            f16x4 r1 = *(const f16x4*)&tw[q * 36 + ch + 4];
            f16x4 r2 = *(const f16x4*)&tw[q * 36 + ch + 8];
            f16x4 r3 = *(const f16x4*)&tw[q * 36 + ch + 12];
            f16x8 o0, o1;
            o0[0]=r0[0]; o0[1]=r0[1]; o0[2]=r0[2]; o0[3]=r0[3];
            o0[4]=r1[0]; o0[5]=r1[1]; o0[6]=r1[2]; o0[7]=r1[3];
            o1[0]=r2[0]; o1[1]=r2[1]; o1[2]=r2[2]; o1[3]=r2[3];
            o1[4]=r3[0]; o1[5]=r3[1]; o1[6]=r3[2]; o1[7]=r3[3];
            f16* dst = Opb + (size_t)(q0 + 32 * w + q) * CDIM + 32 * ct + ch;
            *(f16x8*)(dst)     = o0;
            *(f16x8*)(dst + 8) = o1;
        }
        if (hi == 0) {
            pm[(size_t)(split * NBATCH + n) * SDIM + myq] = m_run;
            pl[(size_t)(split * NBATCH + n) * SDIM + myq] = l_run;
        }
    }
}

// ---------------------------------------------------------------------------
// Kernel 3: MFMA output projection + residual; 4-way split combine fused
// into staging via precomputed per-s scales.
// ---------------------------------------------------------------------------
__global__ __launch_bounds__(256, 2)
void outproj_kernel(const f16* __restrict__ Op,
                    const float* __restrict__ pm,
                    const float* __restrict__ pl,
                    const float* __restrict__ Wo,
                    const float* __restrict__ bo,
                    const float* __restrict__ x,
                    float* __restrict__ out)
{
    const int n  = blockIdx.z;
    const int s0 = blockIdx.x * 128;
    const int m0 = blockIdx.y * 128;

    __shared__ __align__(16) unsigned ys[2][128][34];
    __shared__ float scs[4][128];

    const int t = threadIdx.x, w = t >> 6, l = t & 63, ln = l & 31, hi = l >> 5;
    const int wm = w & 1, wn = w >> 1;

    if (t < 128) {
        const int s = s0 + t;
        float mv[4], lv[4];
        float M = -INFINITY;
        #pragma unroll
        for (int i = 0; i < 4; ++i) {
            mv[i] = pm[((size_t)i * NBATCH + n) * SDIM + s];
            lv[i] = pl[((size_t)i * NBATCH + n) * SDIM + s];
            M = fmaxf(M, mv[i]);
        }
        float d = 0.0f, e[4];
        #pragma unroll
        for (int i = 0; i < 4; ++i) { e[i] = __expf(mv[i] - M); d += e[i] * lv[i]; }
        const float rd = 1.0f / d;
        #pragma unroll
        for (int i = 0; i < 4; ++i) scs[i][t] = e[i] * rd;
    }

    f16x8 aW[2][16];
    #pragma unroll
    for (int mt = 0; mt < 2; ++mt) {
        const float* wr = Wo + (size_t)(m0 + 64 * wm + 32 * mt + ln) * CDIM + 8 * hi;
        #pragma unroll
        for (int j = 0; j < 16; ++j) {
            float4 u0 = *(const float4*)(wr + 16 * j);
            float4 u1 = *(const float4*)(wr + 16 * j + 4);
            f16x8 v;
            v[0] = (f16)u0.x; v[1] = (f16)u0.y; v[2] = (f16)u0.z; v[3] = (f16)u0.w;
            v[4] = (f16)u1.x; v[5] = (f16)u1.y; v[6] = (f16)u1.z; v[7] = (f16)u1.w;
            aW[mt][j] = v;
        }
    }

    f32x16 acc[2][2];
    #pragma unroll
    for (int a = 0; a < 2; ++a)
        #pragma unroll
        for (int b = 0; b < 2; ++b)
            #pragma unroll
            for (int r = 0; r < 16; ++r) acc[a][b][r] = 0.0f;

    const f16* Opb[4];
    #pragma unroll
    for (int i = 0; i < 4; ++i)
        Opb[i] = Op + ((size_t)i * NBATCH + n) * SDIM * CDIM;

    __syncthreads();

    f16x8 yv[4];
#define OLOAD(k0)                                                             \
    { _Pragma("unroll")                                                       \
      for (int u4 = 0; u4 < 4; ++u4) {                                        \
          const int u = u4 * 256 + t;                                         \
          const int kg = u & 7, sl = u >> 3;                                  \
          const size_t off = (size_t)(s0 + sl) * CDIM + (k0) + 8 * kg;        \
          f16x8 a0 = *(const f16x8*)(Opb[0] + off);                           \
          f16x8 a1 = *(const f16x8*)(Opb[1] + off);                           \
          f16x8 a2 = *(const f16x8*)(Opb[2] + off);                           \
          f16x8 a3 = *(const f16x8*)(Opb[3] + off);                           \
          const float c0 = scs[0][sl], c1 = scs[1][sl];                       \
          const float c2 = scs[2][sl], c3 = scs[3][sl];                       \
          f16x8 r;                                                            \
          _Pragma("unroll")                                                   \
          for (int e = 0; e < 8; ++e)                                         \
              r[e] = (f16)(c0 * (float)a0[e] + c1 * (float)a1[e] +            \
                           c2 * (float)a2[e] + c3 * (float)a3[e]);            \
          yv[u4] = r; } }
#define OWRITE(b)                                                             \
    { _Pragma("unroll")                                                       \
      for (int u4 = 0; u4 < 4; ++u4) {                                        \
          const int u = u4 * 256 + t;                                         \
          const int kg = u & 7, sl = u >> 3;                                  \
          CV8 cv; cv.v = yv[u4];                                              \
          *(uint2*)&ys[b][sl][4 * kg]     = cv.q[0];                          \
          *(uint2*)&ys[b][sl][4 * kg + 2] = cv.q[1]; } }

    OLOAD(0);
    for (int ci = 0; ci < 4; ++ci) {
        const int b = ci & 1;
        OWRITE(b);
        __syncthreads();
        if (ci < 3) OLOAD((ci + 1) * 64);
        #pragma unroll
        for (int j = 0; j < 4; ++j) {
            f16x8 bx[2];
            #pragma unroll
            for (int nt = 0; nt < 2; ++nt) {
                const unsigned* pr = &ys[b][64 * wn + 32 * nt + ln][8 * j + 4 * hi];
                f16x4 lo = *(const f16x4*)pr;
                f16x4 h4 = *(const f16x4*)(pr + 2);
                f16x8 bb;
                bb[0]=lo[0]; bb[1]=lo[1]; bb[2]=lo[2]; bb[3]=lo[3];
                bb[4]=h4[0]; bb[5]=h4[1]; bb[6]=h4[2]; bb[7]=h4[3];
                bx[nt] = bb;
            }
            #pragma unroll
            for (int mt = 0; mt < 2; ++mt)
                #pragma unroll
                for (int nt = 0; nt < 2; ++nt)
                    acc[mt][nt] = __builtin_amdgcn_mfma_f32_32x32x16_f16(
                        aW[mt][ci * 4 + j], bx[nt], acc[mt][nt], 0, 0, 0);
        }
    }
#undef OLOAD
#undef OWRITE

    const float* xb = x + (size_t)n * CDIM * SDIM;
    float* ob = out + (size_t)n * CDIM * SDIM;
    #pragma unroll
    for (int mt = 0; mt < 2; ++mt)
        #pragma unroll
        for (int r = 0; r < 16; ++r) {
            const int c = m0 + 64 * wm + 32 * mt + (r & 3) + 8 * (r >> 2) + 4 * hi;
            const float bv = bo[c];
            #pragma unroll
            for (int nt = 0; nt < 2; ++nt) {
                const size_t idx = (size_t)c * SDIM + s0 + 64 * wn + 32 * nt + ln;
                ob[idx] = acc[mt][nt][r] + bv + xb[idx];
            }
        }
}

// ---------------------------------------------------------------------------
extern "C" void kernel_launch(void* const* d_in, const int* in_sizes, int n_in,
                              void* d_out, int out_size, void* d_ws, size_t ws_size,
                              hipStream_t stream)
{
    const float* x  = (const float*)d_in[0];
    const float* Wg = (const float*)d_in[1];
    const float* bg = (const float*)d_in[2];
    const float* Wt = (const float*)d_in[3];
    const float* bt = (const float*)d_in[4];
    const float* Wp = (const float*)d_in[5];
    const float* bp = (const float*)d_in[6];
    const float* Wo = (const float*)d_in[7];
    const float* bo = (const float*)d_in[8];

    const size_t half_buf = (size_t)NBATCH * CDIM * SDIM * sizeof(f16);   // 8 MB
    const size_t mlbuf    = (size_t)4 * NBATCH * SDIM * sizeof(float);    // 256 KB
    char* wsb = (char*)d_ws;
    f16*   theta = (f16*)(wsb);
    f16*   phi   = (f16*)(wsb + half_buf);
    f16*   g     = (f16*)(wsb + 2 * half_buf);
    f16*   Op    = (f16*)(wsb + 3 * half_buf);               // 4 splits, 32 MB
    float* pm    = (float*)(wsb + 7 * half_buf);
    float* pl    = (float*)(wsb + 7 * half_buf + mlbuf);
    float* out   = (float*)d_out;

    proj_kernel<<<dim3(SDIM / 128, CDIM / 128, NBATCH * 3), 256, 0, stream>>>(
        x, Wt, bt, Wp, bp, Wg, bg, theta, phi, g);
    attn_kernel<<<dim3(NBATCH * (SDIM / 128), 4), 256, 0, stream>>>(
        theta, phi, g, Op, pm, pl);
    outproj_kernel<<<dim3(SDIM / 128, CDIM / 128, NBATCH), 256, 0, stream>>>(
        Op, pm, pl, Wo, bo, x, out);
}

// Round 9
// 250.427 us; speedup vs baseline: 8.4662x; 1.0144x over previous
//
#include <hip/hip_runtime.h>
#include <math.h>

#define CDIM 256
#define SDIM 4096
#define NBATCH 4

typedef _Float16 f16;
typedef _Float16 f16x4 __attribute__((ext_vector_type(4)));
typedef _Float16 f16x8 __attribute__((ext_vector_type(8)));
typedef float    f32x16 __attribute__((ext_vector_type(16)));

union PK2 { f16 h[2]; unsigned u; };
union CV8 { f16x8 v; uint2 q[2]; };

// async 16B global->LDS DMA; LDS dest wave-uniform base, HW scatters lane*16.
__device__ __forceinline__ void gload_lds16(const f16* gp, void* lp) {
    __builtin_amdgcn_global_load_lds(
        (const __attribute__((address_space(1))) void*)gp,
        (__attribute__((address_space(3))) void*)lp, 16, 0, 0);
}

// MFMA frag model (validated rounds 2-8, mfma_f32_32x32x16_f16):
//   A[m][k]: m=lane&31, frag covers k=16*step+8*(lane>>5)+(0..7)
//   B[k][n]: n=lane&31, same k pattern
//   C/D:     col=lane&31, row=(r&3)+8*(r>>2)+4*(lane>>5)

// ---------------------------------------------------------------------------
// Kernel 1: MFMA 1x1-conv projections. Round 9: BOTH epilogue paths go
// through the LDS transpose tile and store full 256B rows (16 lanes x 16B)
// — round 8's g-path did 2-byte stride-8KB scatters (partial-line RMW).
// ---------------------------------------------------------------------------
__global__ __launch_bounds__(256, 2)
void proj_kernel(const float* __restrict__ x,
                 const float* __restrict__ Wt, const float* __restrict__ bt,
                 const float* __restrict__ Wp, const float* __restrict__ bp,
                 const float* __restrict__ Wg, const float* __restrict__ bg,
                 f16* __restrict__ theta_t, f16* __restrict__ phi_t,
                 f16* __restrict__ g_out)
{
    const int p = blockIdx.z % 3;
    const int n = blockIdx.z / 3;
    const float* W    = (p == 0) ? Wt : (p == 1) ? Wp : Wg;
    const float* bias = (p == 0) ? bt : (p == 1) ? bp : bg;
    const float* xb = x + (size_t)n * CDIM * SDIM;
    const int s0 = blockIdx.x * 128;
    const int m0 = blockIdx.y * 128;

    __shared__ __align__(16) char smraw[34816];
    unsigned (*xs)[128][34] = reinterpret_cast<unsigned (*)[128][34]>(smraw);
    f16 (*tr)[136]          = reinterpret_cast<f16 (*)[136]>(smraw);

    const int t = threadIdx.x, w = t >> 6, l = t & 63, ln = l & 31, hi = l >> 5;
    const int wm = w & 1, wn = w >> 1;

    f16x8 aW[2][16];
    #pragma unroll
    for (int mt = 0; mt < 2; ++mt) {
        const float* wr = W + (size_t)(m0 + 64 * wm + 32 * mt + ln) * CDIM + 8 * hi;
        #pragma unroll
        for (int j = 0; j < 16; ++j) {
            float4 u0 = *(const float4*)(wr + 16 * j);
            float4 u1 = *(const float4*)(wr + 16 * j + 4);
            f16x8 v;
            v[0] = (f16)u0.x; v[1] = (f16)u0.y; v[2] = (f16)u0.z; v[3] = (f16)u0.w;
            v[4] = (f16)u1.x; v[5] = (f16)u1.y; v[6] = (f16)u1.z; v[7] = (f16)u1.w;
            aW[mt][j] = v;
        }
    }

    f32x16 acc[2][2];
    #pragma unroll
    for (int a = 0; a < 2; ++a)
        #pragma unroll
        for (int b = 0; b < 2; ++b)
            #pragma unroll
            for (int r = 0; r < 16; ++r) acc[a][b][r] = 0.0f;

    const int sL = t & 127;
    const int kB = (t >> 7) * 32;

    float xv[32];
#define PLOAD(k0)                                                             \
    { _Pragma("unroll")                                                       \
      for (int i = 0; i < 32; ++i)                                            \
          xv[i] = xb[(size_t)((k0) + kB + i) * SDIM + s0 + sL]; }
#define PWRITE(b)                                                             \
    { _Pragma("unroll")                                                       \
      for (int m = 0; m < 16; ++m) {                                          \
          PK2 pk; pk.h[0] = (f16)xv[2 * m]; pk.h[1] = (f16)xv[2 * m + 1];     \
          xs[b][sL][(kB >> 1) + m] = pk.u; } }

    PLOAD(0);
    for (int ci = 0; ci < 4; ++ci) {
        const int b = ci & 1;
        PWRITE(b);
        __syncthreads();
        if (ci < 3) PLOAD((ci + 1) * 64);
        #pragma unroll
        for (int j = 0; j < 4; ++j) {
            f16x8 bx[2];
            #pragma unroll
            for (int nt = 0; nt < 2; ++nt) {
                const unsigned* pr = &xs[b][64 * wn + 32 * nt + ln][8 * j + 4 * hi];
                f16x4 lo = *(const f16x4*)pr;
                f16x4 h4 = *(const f16x4*)(pr + 2);
                f16x8 bb;
                bb[0]=lo[0]; bb[1]=lo[1]; bb[2]=lo[2]; bb[3]=lo[3];
                bb[4]=h4[0]; bb[5]=h4[1]; bb[6]=h4[2]; bb[7]=h4[3];
                bx[nt] = bb;
            }
            #pragma unroll
            for (int mt = 0; mt < 2; ++mt)
                #pragma unroll
                for (int nt = 0; nt < 2; ++nt)
                    acc[mt][nt] = __builtin_amdgcn_mfma_f32_32x32x16_f16(
                        aW[mt][ci * 4 + j], bx[nt], acc[mt][nt], 0, 0, 0);
        }
    }
#undef PLOAD
#undef PWRITE

    float bv[2][16];
    #pragma unroll
    for (int mt = 0; mt < 2; ++mt)
        #pragma unroll
        for (int r = 0; r < 16; ++r)
            bv[mt][r] = bias[m0 + 64 * wm + 32 * mt + (r & 3) + 8 * (r >> 2) + 4 * hi];

    __syncthreads();   // all compute reads of xs done before tr reuse
    if (p < 2) {
        // tr[s][c]
        #pragma unroll
        for (int mt = 0; mt < 2; ++mt)
            #pragma unroll
            for (int nt = 0; nt < 2; ++nt)
                #pragma unroll
                for (int r = 0; r < 16; ++r)
                    tr[64 * wn + 32 * nt + ln]
                      [64 * wm + 32 * mt + (r & 3) + 8 * (r >> 2) + 4 * hi] =
                        (f16)(acc[mt][nt][r] + bv[mt][r]);
        __syncthreads();
        f16* out = ((p == 0) ? theta_t : phi_t) + (size_t)n * SDIM * CDIM;
        #pragma unroll
        for (int ps = 0; ps < 8; ++ps) {
            const int id  = ps * 256 + t;
            const int row = id >> 4;          // s index 0..127
            const int c8  = id & 15;          // 16B chunk within row
            *(f16x8*)&out[(size_t)(s0 + row) * CDIM + m0 + c8 * 8] =
                *(const f16x8*)&tr[row][c8 * 8];
        }
    } else {
        // tr[c][s]
        #pragma unroll
        for (int mt = 0; mt < 2; ++mt)
            #pragma unroll
            for (int nt = 0; nt < 2; ++nt)
                #pragma unroll
                for (int r = 0; r < 16; ++r)
                    tr[64 * wm + 32 * mt + (r & 3) + 8 * (r >> 2) + 4 * hi]
                      [64 * wn + 32 * nt + ln] =
                        (f16)(acc[mt][nt][r] + bv[mt][r]);
        __syncthreads();
        f16* out = g_out + (size_t)n * CDIM * SDIM;
        #pragma unroll
        for (int ps = 0; ps < 8; ++ps) {
            const int id  = ps * 256 + t;
            const int row = id >> 4;          // chan 0..127
            const int s8  = id & 15;
            *(f16x8*)&out[(size_t)(m0 + row) * SDIM + s0 + s8 * 8] =
                *(const f16x8*)&tr[row][s8 * 8];
        }
    }
}

// ---------------------------------------------------------------------------
// Kernel 2: MFMA flash attention (round 8 structure, validated). Round 9:
// lazy-max online softmax — running max only advances when the chunk max
// exceeds it by >4 (p <= e^4 fits f16), so the 128-reg O rescale triggers
// a handful of times per 32 chunks instead of nearly every chunk.
// ---------------------------------------------------------------------------
__global__ __launch_bounds__(256, 2)
void attn_kernel(const f16* __restrict__ theta,
                 const f16* __restrict__ phi,
                 const f16* __restrict__ g,
                 f16* __restrict__ Op,       // [4][n][s][c] unnormalized f16
                 float* __restrict__ pm,     // [4][n][s]
                 float* __restrict__ pl)     // [4][n][s]
{
    const int bx    = blockIdx.x;
    const int n     = bx >> 5;
    const int q0    = (bx & 31) * 128;
    const int split = blockIdx.y;
    const int koff  = split * (SDIM / 4);
    const int NCH   = (SDIM / 4) / 32;      // 32 chunks of 32 keys

    __shared__ f16x8 bufP[2][1024];         // 32 KB phi [key][grp^key]
    __shared__ f16x8 bufG[2][1024];         // 32 KB G   [chan][kg swizzled]

    const int t  = threadIdx.x;
    const int w  = t >> 6;
    const int l  = t & 63;
    const int ln = l & 31;
    const int hi = l >> 5;

    const f16* thb = theta + (size_t)n * SDIM * CDIM;
    const f16* phb = phi   + (size_t)n * SDIM * CDIM;
    const f16* gb  = g     + (size_t)n * CDIM * SDIM;

    const int myq = q0 + 32 * w + ln;

    f16x8 bT[16];
    {
        const f16* ap = thb + (size_t)myq * CDIM + hi * 8;
        #pragma unroll
        for (int j = 0; j < 16; ++j)
            bT[j] = *(const f16x8*)(ap + 16 * j);
    }

    f32x16 O[8];
    #pragma unroll
    for (int ct = 0; ct < 8; ++ct)
        #pragma unroll
        for (int r = 0; r < 16; ++r) O[ct][r] = 0.0f;

    float m_run = -INFINITY, l_run = 0.0f;

#define ISSUE_CHUNK(k0, b)                                                    \
    {                                                                         \
        _Pragma("unroll")                                                     \
        for (int it = 0; it < 4; ++it) {                                      \
            const int slot = w * 256 + it * 64 + l;                           \
            const int key  = slot >> 5;                                       \
            const int grp  = (slot & 31) ^ key;                               \
            gload_lds16(phb + (size_t)((k0) + key) * CDIM + grp * 8,          \
                        &bufP[b][w * 256 + it * 64]);                         \
        }                                                                     \
        _Pragma("unroll")                                                     \
        for (int it = 0; it < 4; ++it) {                                      \
            const int slot = w * 256 + it * 64 + l;                           \
            const int chan = slot >> 2;                                       \
            const int kg   = (slot & 3) ^ (chan & 3) ^ ((chan >> 2) & 3);     \
            gload_lds16(gb + (size_t)chan * SDIM + (k0) + kg * 8,             \
                        &bufG[b][w * 256 + it * 64]);                         \
        }                                                                     \
    }

    ISSUE_CHUNK(koff, 0);

    for (int ci = 0; ci < NCH; ++ci) {
        const int b = ci & 1;
        __syncthreads();   // drains DMA for chunk ci; frees buffer b^1
        if (ci + 1 < NCH) ISSUE_CHUNK(koff + (ci + 1) * 32, b ^ 1);

        // ---- S^T = phi x theta^T : 32 keys x 32 q, K=256 ----
        f32x16 sC;
        #pragma unroll
        for (int r = 0; r < 16; ++r) sC[r] = 0.0f;
        #pragma unroll
        for (int j = 0; j < 16; ++j) {
            const int grp = 2 * j + hi;
            f16x8 a = bufP[b][ln * 32 + (grp ^ ln)];
            sC = __builtin_amdgcn_mfma_f32_32x32x16_f16(a, bT[j], sC, 0, 0, 0);
        }

        // ---- lazy-max in-register online softmax ----
        float mx = sC[0];
        #pragma unroll
        for (int r = 1; r < 16; ++r) mx = fmaxf(mx, sC[r]);
        mx = fmaxf(mx, __shfl_xor(mx, 32));
        const float mn = (mx > m_run + 4.0f) ? mx : m_run;  // lazy advance
        const float al = __expf(m_run - mn);                // ==1.0 if held
        m_run = mn;
        float sum = 0.0f;
        #pragma unroll
        for (int r = 0; r < 16; ++r) {
            sC[r] = __expf(sC[r] - mn);    // <= e^4 = 54.6, f16-safe
            sum += sC[r];
        }
        sum += __shfl_xor(sum, 32);
        l_run = l_run * al + sum;

        if (__any(al != 1.0f)) {
            #pragma unroll
            for (int ct = 0; ct < 8; ++ct)
                #pragma unroll
                for (int r = 0; r < 16; ++r) O[ct][r] *= al;
        }

        // ---- repack P to PV B-frags: pf[ks][i] = P[key=16ks+8hi+i][myq] ----
        f16x8 pf[2];
        #pragma unroll
        for (int ks = 0; ks < 2; ++ks) {
            #pragma unroll
            for (int j = 0; j < 4; ++j) {
                const float own = hi ? sC[8 * ks + 4 + j] : sC[8 * ks + j];
                const float oth = hi ? sC[8 * ks + j]     : sC[8 * ks + 4 + j];
                const float par = __shfl_xor(oth, 32);
                pf[ks][j]     = (f16)(hi ? par : own);
                pf[ks][4 + j] = (f16)(hi ? own : par);
            }
        }

        // ---- PV: O^T += G x P^T (256 chan x 32 q, K=32 keys) ----
        #pragma unroll
        for (int ks = 0; ks < 2; ++ks) {
            const int kg = 2 * ks + hi;
            #pragma unroll
            for (int ct = 0; ct < 8; ++ct) {
                const int chan = 32 * ct + ln;
                f16x8 ga = bufG[b][chan * 4 + (kg ^ (ln & 3) ^ ((ln >> 2) & 3))];
                O[ct] = __builtin_amdgcn_mfma_f32_32x32x16_f16(ga, pf[ks], O[ct], 0, 0, 0);
            }
        }
    }
#undef ISSUE_CHUNK

    // ---- epilogue: per-wave LDS transpose -> Op (s,c) f16, + (m,l) ----
    __syncthreads();
    {
        f16* tw = (f16*)bufP + (size_t)w * 1152;   // per-wave [32 q][36 c]
        f16* Opb = Op + ((size_t)(split * NBATCH + n)) * SDIM * CDIM;
        const int q  = l >> 1;
        const int ch = (l & 1) * 16;
        #pragma unroll
        for (int ct = 0; ct < 8; ++ct) {
            #pragma unroll
            for (int q4 = 0; q4 < 4; ++q4) {
                f16x4 v;
                v[0] = (f16)O[ct][4 * q4 + 0];
                v[1] = (f16)O[ct][4 * q4 + 1];
                v[2] = (f16)O[ct][4 * q4 + 2];
                v[3] = (f16)O[ct][4 * q4 + 3];
                *(f16x4*)&tw[ln * 36 + 8 * q4 + 4 * hi] = v;
            }
            f16x4 r0 = *(const f16x4*)&tw[q * 36 + ch + 0];
            f16x4 r1 = *(const f16x4*)&tw[q * 36 + ch + 4];
            f16x4 r2 = *(const f16x4*)&tw[q * 36 + ch + 8];
            f16x4 r3 = *(const f16x4*)&tw[q * 36 + ch + 12];
            f16x8 o0, o1;
            o0[0]=r0[0]; o0[1]=r0[1]; o0[2]=r0[2]; o0[3]=r0[3];
            o0[4]=r1[0]; o0[5]=r1[1]; o0[6]=r1[2]; o0[7]=r1[3];
            o1[0]=r2[0]; o1[1]=r2[1]; o1[2]=r2[2]; o1[3]=r2[3];
            o1[4]=r3[0]; o1[5]=r3[1]; o1[6]=r3[2]; o1[7]=r3[3];
            f16* dst = Opb + (size_t)(q0 + 32 * w + q) * CDIM + 32 * ct + ch;
            *(f16x8*)(dst)     = o0;
            *(f16x8*)(dst + 8) = o1;
        }
        if (hi == 0) {
            pm[(size_t)(split * NBATCH + n) * SDIM + myq] = m_run;
            pl[(size_t)(split * NBATCH + n) * SDIM + myq] = l_run;
        }
    }
}

// ---------------------------------------------------------------------------
// Kernel 3: MFMA output projection + residual; 4-way split combine fused
// into staging. Round 9: tile 128m x 64s -> 512 blocks = 2 blocks/CU
// (was 256 blocks = 1/CU).
// ---------------------------------------------------------------------------
__global__ __launch_bounds__(256, 2)
void outproj_kernel(const f16* __restrict__ Op,
                    const float* __restrict__ pm,
                    const float* __restrict__ pl,
                    const float* __restrict__ Wo,
                    const float* __restrict__ bo,
                    const float* __restrict__ x,
                    float* __restrict__ out)
{
    const int n  = blockIdx.z;
    const int s0 = blockIdx.x * 64;
    const int m0 = blockIdx.y * 128;

    __shared__ __align__(16) unsigned ys[2][64][34];
    __shared__ float scs[4][64];

    const int t = threadIdx.x, w = t >> 6, l = t & 63, ln = l & 31, hi = l >> 5;
    const int wm = w & 1, wn = w >> 1;

    if (t < 64) {
        const int s = s0 + t;
        float mv[4], lv[4];
        float M = -INFINITY;
        #pragma unroll
        for (int i = 0; i < 4; ++i) {
            mv[i] = pm[((size_t)i * NBATCH + n) * SDIM + s];
            lv[i] = pl[((size_t)i * NBATCH + n) * SDIM + s];
            M = fmaxf(M, mv[i]);
        }
        float d = 0.0f, e[4];
        #pragma unroll
        for (int i = 0; i < 4; ++i) { e[i] = __expf(mv[i] - M); d += e[i] * lv[i]; }
        const float rd = 1.0f / d;
        #pragma unroll
        for (int i = 0; i < 4; ++i) scs[i][t] = e[i] * rd;
    }

    f16x8 aW[2][16];
    #pragma unroll
    for (int mt = 0; mt < 2; ++mt) {
        const float* wr = Wo + (size_t)(m0 + 64 * wm + 32 * mt + ln) * CDIM + 8 * hi;
        #pragma unroll
        for (int j = 0; j < 16; ++j) {
            float4 u0 = *(const float4*)(wr + 16 * j);
            float4 u1 = *(const float4*)(wr + 16 * j + 4);
            f16x8 v;
            v[0] = (f16)u0.x; v[1] = (f16)u0.y; v[2] = (f16)u0.z; v[3] = (f16)u0.w;
            v[4] = (f16)u1.x; v[5] = (f16)u1.y; v[6] = (f16)u1.z; v[7] = (f16)u1.w;
            aW[mt][j] = v;
        }
    }

    f32x16 acc[2];
    #pragma unroll
    for (int a = 0; a < 2; ++a)
        #pragma unroll
        for (int r = 0; r < 16; ++r) acc[a][r] = 0.0f;

    const f16* Opb[4];
    #pragma unroll
    for (int i = 0; i < 4; ++i)
        Opb[i] = Op + ((size_t)i * NBATCH + n) * SDIM * CDIM;

    __syncthreads();   // scs ready

    f16x8 yv[2];
#define OLOAD(k0)                                                             \
    { _Pragma("unroll")                                                       \
      for (int u2 = 0; u2 < 2; ++u2) {                                        \
          const int u = u2 * 256 + t;                                         \
          const int kg = u & 7, sl = u >> 3;                                  \
          const size_t off = (size_t)(s0 + sl) * CDIM + (k0) + 8 * kg;        \
          f16x8 a0 = *(const f16x8*)(Opb[0] + off);                           \
          f16x8 a1 = *(const f16x8*)(Opb[1] + off);                           \
          f16x8 a2 = *(const f16x8*)(Opb[2] + off);                           \
          f16x8 a3 = *(const f16x8*)(Opb[3] + off);                           \
          const float c0 = scs[0][sl], c1 = scs[1][sl];                       \
          const float c2 = scs[2][sl], c3 = scs[3][sl];                       \
          f16x8 r;                                                            \
          _Pragma("unroll")                                                   \
          for (int e = 0; e < 8; ++e)                                         \
              r[e] = (f16)(c0 * (float)a0[e] + c1 * (float)a1[e] +            \
                           c2 * (float)a2[e] + c3 * (float)a3[e]);            \
          yv[u2] = r; } }
#define OWRITE(b)                                                             \
    { _Pragma("unroll")                                                       \
      for (int u2 = 0; u2 < 2; ++u2) {                                        \
          const int u = u2 * 256 + t;                                         \
          const int kg = u & 7, sl = u >> 3;                                  \
          CV8 cv; cv.v = yv[u2];                                              \
          *(uint2*)&ys[b][sl][4 * kg]     = cv.q[0];                          \
          *(uint2*)&ys[b][sl][4 * kg + 2] = cv.q[1]; } }

    OLOAD(0);
    for (int ci = 0; ci < 4; ++ci) {
        const int b = ci & 1;
        OWRITE(b);
        __syncthreads();
        if (ci < 3) OLOAD((ci + 1) * 64);
        #pragma unroll
        for (int j = 0; j < 4; ++j) {
            const unsigned* pr = &ys[b][32 * wn + ln][8 * j + 4 * hi];
            f16x4 lo = *(const f16x4*)pr;
            f16x4 h4 = *(const f16x4*)(pr + 2);
            f16x8 bb;
            bb[0]=lo[0]; bb[1]=lo[1]; bb[2]=lo[2]; bb[3]=lo[3];
            bb[4]=h4[0]; bb[5]=h4[1]; bb[6]=h4[2]; bb[7]=h4[3];
            #pragma unroll
            for (int mt = 0; mt < 2; ++mt)
                acc[mt] = __builtin_amdgcn_mfma_f32_32x32x16_f16(
                    aW[mt][ci * 4 + j], bb, acc[mt], 0, 0, 0);
        }
    }
#undef OLOAD
#undef OWRITE

    const float* xb = x + (size_t)n * CDIM * SDIM;
    float* ob = out + (size_t)n * CDIM * SDIM;
    #pragma unroll
    for (int mt = 0; mt < 2; ++mt)
        #pragma unroll
        for (int r = 0; r < 16; ++r) {
            const int c = m0 + 64 * wm + 32 * mt + (r & 3) + 8 * (r >> 2) + 4 * hi;
            const float bv = bo[c];
            const size_t idx = (size_t)c * SDIM + s0 + 32 * wn + ln;
            ob[idx] = acc[mt][r] + bv + xb[idx];
        }
}

// ---------------------------------------------------------------------------
extern "C" void kernel_launch(void* const* d_in, const int* in_sizes, int n_in,
                              void* d_out, int out_size, void* d_ws, size_t ws_size,
                              hipStream_t stream)
{
    const float* x  = (const float*)d_in[0];
    const float* Wg = (const float*)d_in[1];
    const float* bg = (const float*)d_in[2];
    const float* Wt = (const float*)d_in[3];
    const float* bt = (const float*)d_in[4];
    const float* Wp = (const float*)d_in[5];
    const float* bp = (const float*)d_in[6];
    const float* Wo = (const float*)d_in[7];
    const float* bo = (const float*)d_in[8];

    const size_t half_buf = (size_t)NBATCH * CDIM * SDIM * sizeof(f16);   // 8 MB
    const size_t mlbuf    = (size_t)4 * NBATCH * SDIM * sizeof(float);    // 256 KB
    char* wsb = (char*)d_ws;
    f16*   theta = (f16*)(wsb);
    f16*   phi   = (f16*)(wsb + half_buf);
    f16*   g     = (f16*)(wsb + 2 * half_buf);
    f16*   Op    = (f16*)(wsb + 3 * half_buf);               // 4 splits, 32 MB
    float* pm    = (float*)(wsb + 7 * half_buf);
    float* pl    = (float*)(wsb + 7 * half_buf + mlbuf);
    float* out   = (float*)d_out;

    proj_kernel<<<dim3(SDIM / 128, CDIM / 128, NBATCH * 3), 256, 0, stream>>>(
        x, Wt, bt, Wp, bp, Wg, bg, theta, phi, g);
    attn_kernel<<<dim3(NBATCH * (SDIM / 128), 4), 256, 0, stream>>>(
        theta, phi, g, Op, pm, pl);
    outproj_kernel<<<dim3(SDIM / 64, CDIM / 128, NBATCH), 256, 0, stream>>>(
        Op, pm, pl, Wo, bo, x, out);
}